// Round 9
// baseline (498.429 us; speedup 1.0000x reference)
//
#include <hip/hip_runtime.h>
#include <stdint.h>

#define BT 4096      // tokens total (8*512)
#define KC 8192      // centroids
#define DD 768       // feature dim
#define T_STRIDE 513 // rep row stride (skip token 0 per batch)
#define DELTA 6.0f   // candidate window; worst-case fp16 approx error chain <= 2.4

typedef _Float16 f16x8 __attribute__((ext_vector_type(8)));
typedef _Float16 f16x4 __attribute__((ext_vector_type(4)));
typedef float    f32x4 __attribute__((ext_vector_type(4)));

#define GLD16(gp, lp)                                                       \
  __builtin_amdgcn_global_load_lds(                                         \
      (__attribute__((address_space(1))) void*)(gp),                        \
      (__attribute__((address_space(3))) void*)(lp), 16, 0, 0)

__device__ __forceinline__ unsigned int sortable_bits(float d) {
  unsigned int bits = __float_as_uint(d);
  return (bits & 0x80000000u) ? ~bits : (bits | 0x80000000u);
}

// ------- D1: split fp32 -> fp16 + exact fp32 centroid norms (vectorized) -------
// (norm_rep is NOT needed: it is a per-token constant in the argmin)
__global__ __launch_bounds__(256) void split_norm_kernel(
    const float* __restrict__ rep, const float* __restrict__ cent,
    _Float16* __restrict__ a_hi, _Float16* __restrict__ b_hi,
    float* __restrict__ norm_cent) {
  int wid  = (blockIdx.x * blockDim.x + threadIdx.x) >> 6;
  int lane = threadIdx.x & 63;
  if (wid < BT) {
    int b = wid >> 9, tt = wid & 511;
    const float4* s4 = (const float4*)(rep + (size_t)(b * T_STRIDE + 1 + tt) * DD);
    f16x4* h4 = (f16x4*)(a_hi + (size_t)wid * DD);
    #pragma unroll
    for (int i = 0; i < 3; ++i) {
      float4 v = s4[lane + i * 64];
      f16x4 h;
      h[0] = (_Float16)v.x; h[1] = (_Float16)v.y;
      h[2] = (_Float16)v.z; h[3] = (_Float16)v.w;
      h4[lane + i * 64] = h;
    }
  } else {
    int k = wid - BT;
    if (k >= KC) return;
    const float4* s4 = (const float4*)(cent + (size_t)k * DD);
    f16x4* h4 = (f16x4*)(b_hi + (size_t)k * DD);
    float s = 0.f;
    #pragma unroll
    for (int i = 0; i < 3; ++i) {
      float4 v = s4[lane + i * 64];
      s += v.x * v.x + v.y * v.y + v.z * v.z + v.w * v.w;
      f16x4 h;
      h[0] = (_Float16)v.x; h[1] = (_Float16)v.y;
      h[2] = (_Float16)v.z; h[3] = (_Float16)v.w;
      h4[lane + i * 64] = h;
    }
    #pragma unroll
    for (int off = 32; off; off >>= 1) s += __shfl_down(s, off, 64);
    if (lane == 0) norm_cent[k] = s;
  }
}

// ------- D2: r6 GEMM (A=cents, B=tokens, BK=64 swizzled) + last-block refine -------
// grid: 2048 blocks; bm = blk & 63 (centroid tile), bn = blk >> 6 (token tile).
// Cross-block data (LMin/Mask) moves ONLY through device-scope atomics.
__global__ __launch_bounds__(256, 2) void gemm_refine(
    const _Float16* __restrict__ a_hi, const _Float16* __restrict__ b_hi,
    const float* __restrict__ rep, const float* __restrict__ cent,
    const float* __restrict__ norm_cent,
    unsigned* __restrict__ LMin,               // f32 bits, [BT][128]
    unsigned long long* __restrict__ Mask,     // [BT][128]
    unsigned* __restrict__ cnt,                // [32] arrival counters per bn
    float* __restrict__ out_tokens, float* __restrict__ out_q) {
  __shared__ _Float16 As[128 * 64];  // centroid tile (16 KiB)
  __shared__ _Float16 Bs[128 * 64];  // token tile    (16 KiB)
  __shared__ unsigned s_old;

  const int tid = threadIdx.x;
  const int w = tid >> 6, l = tid & 63;
  const int bn  = blockIdx.x >> 6;
  const int bm0 = (blockIdx.x & 63) * 128;   // centroid base
  const int bn0 = bn * 128;                  // token base

  // staging: instr j covers 8 rows x 128B; lane l -> row j*8+(l>>3),
  // global chunk c = (l&7) ^ (l>>3)  (XOR swizzle; LDS dest stays lane*16B)
  const int srow   = l >> 3;
  const int schunk = (l & 7) ^ srow;
  size_t goffA[4], goffB[4];
  _Float16 *ldsA[4], *ldsB[4];
  #pragma unroll
  for (int j2 = 0; j2 < 4; ++j2) {
    const int j = w * 4 + j2;
    goffA[j2] = (size_t)(bm0 + j * 8 + srow) * DD + schunk * 8;
    goffB[j2] = (size_t)(bn0 + j * 8 + srow) * DD + schunk * 8;
    ldsA[j2] = As + j * 8 * 64;
    ldsB[j2] = Bs + j * 8 * 64;
  }

  const int wm = (w & 1) * 64;   // centroid offset within tile
  const int wn = (w >> 1) * 64;  // token offset within tile
  const int sub = l & 15, q = l >> 4;

  f32x4 acc[4][4] = {};  // [mt: cent subtile][nt: token subtile]

  for (int kin = 0; kin < DD; kin += 64) {
    __syncthreads();   // previous frag reads done before overwrite
    #pragma unroll
    for (int j2 = 0; j2 < 4; ++j2) {
      GLD16(b_hi + goffA[j2] + kin, ldsA[j2]);
      GLD16(a_hi + goffB[j2] + kin, ldsB[j2]);
    }
    __syncthreads();   // drain vmcnt -> LDS visible

    #pragma unroll
    for (int kk = 0; kk < 2; ++kk) {
      f16x8 af[4], bfr[4];
      #pragma unroll
      for (int i = 0; i < 4; ++i) {
        const int arow = wm + i * 16 + sub;
        const int brow = wn + i * 16 + sub;
        const int c = q + kk * 4;
        af[i]  = *(const f16x8*)(As + arow * 64 + ((c ^ (arow & 7)) * 8));
        bfr[i] = *(const f16x8*)(Bs + brow * 64 + ((c ^ (brow & 7)) * 8));
      }
      #pragma unroll
      for (int mt = 0; mt < 4; ++mt)
        #pragma unroll
        for (int nt = 0; nt < 4; ++nt)
          acc[mt][nt] = __builtin_amdgcn_mfma_f32_16x16x32_f16(
              af[mt], bfr[nt], acc[mt][nt], 0, 0, 0);
    }
  }

  // epilogue: shifted distance d = nc - 2*dot (per-token constant nr dropped).
  // per lane, 16 distances of token (nt,sub) are in-lane (mt x r)
  const int g = (bm0 >> 6) + (w & 1);   // 64-centroid group index
  float ncv[4][4];
  #pragma unroll
  for (int mt = 0; mt < 4; ++mt)
    #pragma unroll
    for (int r = 0; r < 4; ++r)
      ncv[mt][r] = norm_cent[bm0 + wm + mt * 16 + q * 4 + r];

  #pragma unroll
  for (int nt = 0; nt < 4; ++nt) {
    const int t = bn0 + wn + nt * 16 + sub;
    float d[4][4];
    float dmin = 3.4e38f;
    #pragma unroll
    for (int mt = 0; mt < 4; ++mt)
      #pragma unroll
      for (int r = 0; r < 4; ++r) {
        d[mt][r] = ncv[mt][r] - 2.0f * acc[mt][nt][r];
        dmin = fminf(dmin, d[mt][r]);
      }
    dmin = fminf(dmin, __shfl_xor(dmin, 16, 64));
    dmin = fminf(dmin, __shfl_xor(dmin, 32, 64));
    const float thresh = dmin + DELTA;
    unsigned long long pm = 0;
    #pragma unroll
    for (int mt = 0; mt < 4; ++mt)
      #pragma unroll
      for (int r = 0; r < 4; ++r)
        if (d[mt][r] <= thresh) pm |= 1ull << (mt * 16 + q * 4 + r);
    pm |= (unsigned long long)__shfl_xor((long long)pm, 16, 64);
    pm |= (unsigned long long)__shfl_xor((long long)pm, 32, 64);
    if (q == 0) {
      // device-scope coherent stores (write-through; no fence dependence)
      __hip_atomic_store(&LMin[(size_t)t * 128 + g], __float_as_uint(dmin),
                         __ATOMIC_RELAXED, __HIP_MEMORY_SCOPE_AGENT);
      __hip_atomic_store(&Mask[(size_t)t * 128 + g], pm,
                         __ATOMIC_RELAXED, __HIP_MEMORY_SCOPE_AGENT);
    }
  }

  // ---- arrival: last of the 64 bm-blocks for this bn refines its 128 tokens ----
  __threadfence();
  __syncthreads();   // all waves' stores drained before counting
  if (tid == 0)
    s_old = __hip_atomic_fetch_add(&cnt[bn], 1u, __ATOMIC_ACQ_REL,
                                   __HIP_MEMORY_SCOPE_AGENT);
  __syncthreads();
  if (s_old != 63) return;
  __threadfence();

  // ---- refine (r6 wave-per-token, atomic loads): wave w -> tokens bn0+w*32.. ----
  for (int i = 0; i < 32; ++i) {
    const int t = bn0 + w * 32 + i;
    const float lm0 = __uint_as_float(__hip_atomic_load(
        &LMin[(size_t)t * 128 + l], __ATOMIC_RELAXED, __HIP_MEMORY_SCOPE_AGENT));
    const float lm1 = __uint_as_float(__hip_atomic_load(
        &LMin[(size_t)t * 128 + 64 + l], __ATOMIC_RELAXED, __HIP_MEMORY_SCOPE_AGENT));
    float v = fminf(lm0, lm1);
    #pragma unroll
    for (int off = 32; off; off >>= 1) v = fminf(v, __shfl_xor(v, off, 64));
    const float thresh = v + DELTA;
    unsigned long long gm0 = __ballot(lm0 <= thresh);
    unsigned long long gm1 = __ballot(lm1 <= thresh);

    const int b_ = t >> 9, tt = t & 511;
    const float* rrow = rep + (size_t)(b_ * T_STRIDE + 1 + tt) * DD;
    unsigned long long bestE = ~0ull;   // lane 0 authoritative

    #pragma unroll
    for (int half = 0; half < 2; ++half) {
      unsigned long long gmask = half ? gm1 : gm0;
      while (gmask) {
        const int h = __ffsll((unsigned long long)gmask) - 1;
        gmask &= gmask - 1;
        unsigned long long mask = __hip_atomic_load(
            &Mask[(size_t)t * 128 + half * 64 + h], __ATOMIC_RELAXED,
            __HIP_MEMORY_SCOPE_AGENT);
        while (mask) {
          const int bit = __ffsll((unsigned long long)mask) - 1;
          mask &= mask - 1;
          const int k = (half * 64 + h) * 64 + bit;
          const float* crow = cent + (size_t)k * DD;
          float part = 0.f;
          #pragma unroll
          for (int j = 0; j < 12; ++j)
            part += rrow[l + j * 64] * crow[l + j * 64];
          #pragma unroll
          for (int off = 32; off; off >>= 1) part += __shfl_down(part, off, 64);
          if (l == 0) {
            float d = norm_cent[k] - 2.0f * part;   // shifted exact distance
            unsigned long long p =
                ((unsigned long long)sortable_bits(d) << 32) | (unsigned)k;
            if (p < bestE) bestE = p;
          }
        }
      }
    }
    int kb0 = (l == 0) ? (int)(bestE & 0xFFFFFFFFull) : 0;
    const int kbest = __shfl(kb0, 0, 64);
    if (l == 0) out_tokens[t] = (float)kbest;
    const float4* src = (const float4*)(cent + (size_t)kbest * DD);
    float4* dst = (float4*)(out_q + (size_t)t * DD);
    #pragma unroll
    for (int j = 0; j < 3; ++j) dst[l + j * 64] = src[l + j * 64];
  }
}

// ================= tiny-ws fallback: fp32 vector GEMM + argmin =================
#define FBM 64
#define FBN 64
#define FBK 16
#define FNSPLIT 16
__global__ __launch_bounds__(256) void norms_only_kernel(
    const float* __restrict__ rep, const float* __restrict__ cent,
    float* __restrict__ norm_rep, float* __restrict__ norm_cent) {
  int wid  = (blockIdx.x * blockDim.x + threadIdx.x) >> 6;
  int lane = threadIdx.x & 63;
  const float* src;
  float* nd;
  if (wid < BT) {
    int b = wid >> 9, tt = wid & 511;
    src = rep + (size_t)(b * T_STRIDE + 1 + tt) * DD;
    nd = norm_rep + wid;
  } else {
    int k = wid - BT;
    if (k >= KC) return;
    src = cent + (size_t)k * DD;
    nd = norm_cent + k;
  }
  float s = 0.f;
  for (int j = lane; j < DD; j += 64) { float v = src[j]; s += v * v; }
  #pragma unroll
  for (int off = 32; off; off >>= 1) s += __shfl_down(s, off, 64);
  if (lane == 0) *nd = s;
}

__global__ __launch_bounds__(256) void fp32_argmin_gemm(
    const float* __restrict__ rep, const float* __restrict__ cent,
    const float* __restrict__ norm_rep, const float* __restrict__ norm_cent,
    unsigned long long* __restrict__ packed) {
  __shared__ float Asf[FBK][FBM];
  __shared__ float Bsf[FBK][FBN];
  const int tid = threadIdx.x;
  const int m0  = blockIdx.x * FBM;
  const int kbase = blockIdx.y * (KC / FNSPLIT);
  const int tx = tid & 15, ty = tid >> 4;
  const int ldr = tid >> 2, ldc = (tid & 3) * 4;
  const int t_ld = m0 + ldr;
  const float* arow =
      rep + (size_t)((t_ld >> 9) * T_STRIDE + 1 + (t_ld & 511)) * DD + ldc;
  unsigned long long best[4];
  #pragma unroll
  for (int i = 0; i < 4; ++i) best[i] = ~0ull;
  float nr[4];
  #pragma unroll
  for (int i = 0; i < 4; ++i) nr[i] = norm_rep[m0 + ty * 4 + i];
  for (int nt = 0; nt < (KC / FNSPLIT) / FBN; ++nt) {
    const int n0 = kbase + nt * FBN;
    const float* brow = cent + (size_t)(n0 + ldr) * DD + ldc;
    float acc[4][4];
    #pragma unroll
    for (int i = 0; i < 4; ++i)
      #pragma unroll
      for (int j = 0; j < 4; ++j) acc[i][j] = 0.f;
    for (int d0 = 0; d0 < DD; d0 += FBK) {
      float4 av = *(const float4*)(arow + d0);
      float4 bv = *(const float4*)(brow + d0);
      __syncthreads();
      Asf[ldc + 0][ldr] = av.x; Asf[ldc + 1][ldr] = av.y;
      Asf[ldc + 2][ldr] = av.z; Asf[ldc + 3][ldr] = av.w;
      Bsf[ldc + 0][ldr] = bv.x; Bsf[ldc + 1][ldr] = bv.y;
      Bsf[ldc + 2][ldr] = bv.z; Bsf[ldc + 3][ldr] = bv.w;
      __syncthreads();
      #pragma unroll
      for (int kk = 0; kk < FBK; ++kk) {
        float4 a4 = *(const float4*)&Asf[kk][ty * 4];
        float4 b4 = *(const float4*)&Bsf[kk][tx * 4];
        float a[4] = {a4.x, a4.y, a4.z, a4.w};
        float b[4] = {b4.x, b4.y, b4.z, b4.w};
        #pragma unroll
        for (int i = 0; i < 4; ++i)
          #pragma unroll
          for (int j = 0; j < 4; ++j) acc[i][j] += a[i] * b[j];
      }
    }
    #pragma unroll
    for (int i = 0; i < 4; ++i) {
      #pragma unroll
      for (int j = 0; j < 4; ++j) {
        int k = n0 + tx * 4 + j;
        float d = (nr[i] + norm_cent[k]) - 2.0f * acc[i][j];
        unsigned long long p =
            ((unsigned long long)sortable_bits(d) << 32) | (unsigned int)k;
        if (p < best[i]) best[i] = p;
      }
    }
  }
  #pragma unroll
  for (int off = 1; off < 16; off <<= 1) {
    #pragma unroll
    for (int i = 0; i < 4; ++i) {
      unsigned long long o =
          (unsigned long long)__shfl_xor((long long)best[i], off, 64);
      if (o < best[i]) best[i] = o;
    }
  }
  if (tx == 0) {
    #pragma unroll
    for (int i = 0; i < 4; ++i)
      atomicMin(&packed[m0 + ty * 4 + i], best[i]);
  }
}

__global__ __launch_bounds__(192) void gather_kernel(
    const unsigned long long* __restrict__ packed,
    const float* __restrict__ cent,
    float* __restrict__ out_tokens, float* __restrict__ out_q) {
  int t = blockIdx.x;
  unsigned int k = (unsigned int)(packed[t] & 0xFFFFFFFFull);
  if (threadIdx.x == 0) out_tokens[t] = (float)k;
  const float4* src = (const float4*)(cent + (size_t)k * DD);
  float4* dst = (float4*)(out_q + (size_t)t * DD);
  dst[threadIdx.x] = src[threadIdx.x];
}

extern "C" void kernel_launch(void* const* d_in, const int* in_sizes, int n_in,
                              void* d_out, int out_size, void* d_ws, size_t ws_size,
                              hipStream_t stream) {
  const float* rep  = (const float*)d_in[0];   // (8,513,768) fp32
  const float* cent = (const float*)d_in[1];   // (8192,768) fp32
  float* out = (float*)d_out;                  // [tokens(4096) | quantized(4096*768)]

  // fused-path layout: a_hi | b_hi | LMin | Mask | norm_cent | cnt
  const size_t SZ_AH = (size_t)BT * DD * 2;          //  6 MiB
  const size_t SZ_BH = (size_t)KC * DD * 2;          // 12 MiB
  const size_t SZ_LM = (size_t)BT * 128 * 4;         //  2 MiB
  const size_t SZ_MK = (size_t)BT * 128 * 8;         //  4 MiB
  const size_t OFF_NC  = SZ_AH + SZ_BH + SZ_LM + SZ_MK;
  const size_t OFF_CNT = OFF_NC + 32768;
  const size_t WS_A    = OFF_CNT + 256;

  if (ws_size >= WS_A) {
    _Float16* a_hi = (_Float16*)d_ws;
    _Float16* b_hi = (_Float16*)((char*)d_ws + SZ_AH);
    unsigned* LMin = (unsigned*)((char*)d_ws + SZ_AH + SZ_BH);
    unsigned long long* Mask =
        (unsigned long long*)((char*)d_ws + SZ_AH + SZ_BH + SZ_LM);
    float* norm_cent = (float*)((char*)d_ws + OFF_NC);
    unsigned* cnt    = (unsigned*)((char*)d_ws + OFF_CNT);

    hipMemsetAsync(cnt, 0, 32 * sizeof(unsigned), stream);
    split_norm_kernel<<<3072, 256, 0, stream>>>(rep, cent, a_hi, b_hi,
                                                norm_cent);
    gemm_refine<<<2048, 256, 0, stream>>>(a_hi, b_hi, rep, cent, norm_cent,
                                          LMin, Mask, cnt, out, out + BT);
  } else {
    unsigned long long* packed = (unsigned long long*)d_ws;
    float* norm_rep  = (float*)((char*)d_ws + 32768);
    float* norm_cent = (float*)((char*)d_ws + 49152);

    hipMemsetAsync(packed, 0xFF, BT * sizeof(unsigned long long), stream);
    norms_only_kernel<<<3072, 256, 0, stream>>>(rep, cent, norm_rep, norm_cent);
    dim3 grid(BT / FBM, FNSPLIT);
    fp32_argmin_gemm<<<grid, 256, 0, stream>>>(rep, cent, norm_rep, norm_cent,
                                               packed);
    gather_kernel<<<BT, 192, 0, stream>>>(packed, cent, out, out + BT);
  }
}

// Round 10
// 139.707 us; speedup vs baseline: 3.5677x; 3.5677x over previous
//
#include <hip/hip_runtime.h>
#include <stdint.h>

#define BT 4096      // tokens total (8*512)
#define KC 8192      // centroids
#define DD 768       // feature dim
#define T_STRIDE 513 // rep row stride (skip token 0 per batch)
#define DELTA 20.0f  // i8 screen window: err RMS ~0.75 -> ~26 sigma margin

typedef int   v4i  __attribute__((ext_vector_type(4)));
typedef float f32x4 __attribute__((ext_vector_type(4)));

#define GLD16(gp, lp)                                                       \
  __builtin_amdgcn_global_load_lds(                                         \
      (__attribute__((address_space(1))) void*)(gp),                        \
      (__attribute__((address_space(3))) void*)(lp), 16, 0, 0)

__device__ __forceinline__ unsigned int sortable_bits(float d) {
  unsigned int bits = __float_as_uint(d);
  return (bits & 0x80000000u) ? ~bits : (bits | 0x80000000u);
}

// ------- D1: per-row absmax-quantize fp32 -> i8 + scales + exact cent norms -------
__global__ __launch_bounds__(256) void quant_kernel(
    const float* __restrict__ rep, const float* __restrict__ cent,
    int8_t* __restrict__ a8, int8_t* __restrict__ b8,
    float* __restrict__ s_a, float* __restrict__ s_b,
    float* __restrict__ norm_cent) {
  int wid  = (blockIdx.x * blockDim.x + threadIdx.x) >> 6;
  int lane = threadIdx.x & 63;
  const float4* s4;
  int8_t* dst;
  float* sdst;
  float* ndst = nullptr;
  if (wid < BT) {
    int b = wid >> 9, tt = wid & 511;
    s4 = (const float4*)(rep + (size_t)(b * T_STRIDE + 1 + tt) * DD);
    dst = a8 + (size_t)wid * DD;
    sdst = s_a + wid;
  } else {
    int k = wid - BT;
    if (k >= KC) return;
    s4 = (const float4*)(cent + (size_t)k * DD);
    dst = b8 + (size_t)k * DD;
    sdst = s_b + k;
    ndst = norm_cent + k;
  }
  float4 v[3];
  float m = 0.f, nrm = 0.f;
  #pragma unroll
  for (int i = 0; i < 3; ++i) {
    v[i] = s4[lane + i * 64];
    m = fmaxf(m, fmaxf(fmaxf(fabsf(v[i].x), fabsf(v[i].y)),
                       fmaxf(fabsf(v[i].z), fabsf(v[i].w))));
    nrm += v[i].x * v[i].x + v[i].y * v[i].y + v[i].z * v[i].z + v[i].w * v[i].w;
  }
  #pragma unroll
  for (int off = 32; off; off >>= 1) m = fmaxf(m, __shfl_xor(m, off, 64));
  const float rs = (m > 0.f) ? 127.0f / m : 0.f;
  unsigned* d32 = (unsigned*)dst;
  #pragma unroll
  for (int i = 0; i < 3; ++i) {
    int q0 = (int)rintf(v[i].x * rs);
    int q1 = (int)rintf(v[i].y * rs);
    int q2 = (int)rintf(v[i].z * rs);
    int q3 = (int)rintf(v[i].w * rs);
    unsigned pk = (unsigned)(q0 & 255) | ((unsigned)(q1 & 255) << 8) |
                  ((unsigned)(q2 & 255) << 16) | ((unsigned)(q3 & 255) << 24);
    d32[lane + i * 64] = pk;
  }
  if (ndst) {
    #pragma unroll
    for (int off = 32; off; off >>= 1) nrm += __shfl_down(nrm, off, 64);
  }
  if (lane == 0) {
    *sdst = m / 127.0f;
    if (ndst) *ndst = nrm;
  }
}

// ------- D2: i8 MFMA GEMM (A=cents, B=tokens, BK=128 bytes, r6 swizzle) -------
// grid: (KC/128, BT/128) = (64, 32); 256 threads (4 waves, 2x2 of 64x64).
// Screen distance d~ = nc_k - 2*sa_t*sb_k*idot. Emits LMin/Mask per (t, 64-cent group).
__global__ __launch_bounds__(256, 2) void mfma_i8_cand(
    const int8_t* __restrict__ a8,   // tokens [BT][DD]
    const int8_t* __restrict__ b8,   // cents  [KC][DD]
    const float* __restrict__ s_a, const float* __restrict__ s_b,
    const float* __restrict__ norm_cent,
    float* __restrict__ LMin, unsigned long long* __restrict__ Mask) {
  __shared__ __attribute__((aligned(16))) int8_t As[128 * 128];  // cent tile 16KB
  __shared__ __attribute__((aligned(16))) int8_t Bs[128 * 128];  // token tile 16KB

  const int tid = threadIdx.x;
  const int w = tid >> 6, l = tid & 63;
  const int bm0 = blockIdx.x * 128;  // centroid base
  const int bn0 = blockIdx.y * 128;  // token base

  // staging: instr j covers 8 rows x 128B; lane l -> row j*8+(l>>3),
  // global chunk c = (l&7) ^ (l>>3)  (XOR swizzle; LDS dest stays lane*16B)
  const int srow   = l >> 3;
  const int schunk = (l & 7) ^ srow;
  size_t goffA[4], goffB[4];
  int8_t *ldsA[4], *ldsB[4];
  #pragma unroll
  for (int j2 = 0; j2 < 4; ++j2) {
    const int j = w * 4 + j2;
    goffA[j2] = (size_t)(bm0 + j * 8 + srow) * DD + schunk * 16;
    goffB[j2] = (size_t)(bn0 + j * 8 + srow) * DD + schunk * 16;
    ldsA[j2] = As + j * 8 * 128;
    ldsB[j2] = Bs + j * 8 * 128;
  }

  const int wm = (w & 1) * 64;   // centroid offset within tile
  const int wn = (w >> 1) * 64;  // token offset within tile
  const int sub = l & 15, q = l >> 4;

  v4i acc[4][4] = {};  // [mt: cent subtile][nt: token subtile], i32 x4

  for (int kin = 0; kin < DD; kin += 128) {
    __syncthreads();   // previous frag reads done before overwrite
    #pragma unroll
    for (int j2 = 0; j2 < 4; ++j2) {
      GLD16(b8 + goffA[j2] + kin, ldsA[j2]);
      GLD16(a8 + goffB[j2] + kin, ldsB[j2]);
    }
    __syncthreads();   // drain vmcnt -> LDS visible

    #pragma unroll
    for (int kk = 0; kk < 2; ++kk) {
      v4i af[4], bf[4];
      #pragma unroll
      for (int i = 0; i < 4; ++i) {
        const int arow = wm + i * 16 + sub;
        const int brow = wn + i * 16 + sub;
        const int c = q + kk * 4;   // logical 16B chunk for k = kk*64 + q*16
        af[i] = *(const v4i*)(As + arow * 128 + ((c ^ (arow & 7)) * 16));
        bf[i] = *(const v4i*)(Bs + brow * 128 + ((c ^ (brow & 7)) * 16));
      }
      #pragma unroll
      for (int mt = 0; mt < 4; ++mt)
        #pragma unroll
        for (int nt = 0; nt < 4; ++nt)
          asm volatile("v_mfma_i32_16x16x64_i8 %0, %1, %2, %0"
                       : "+v"(acc[mt][nt])
                       : "v"(af[mt]), "v"(bf[nt]));
    }
  }
  // cover MFMA dst latency before VALU reads (inline asm bypasses compiler hazards)
  asm volatile("s_nop 7\n\ts_nop 7\n\ts_nop 7" ::: "memory");

  // epilogue: per lane, 16 screen distances of token (nt,sub) are in-lane (mt x r)
  const int g = (bm0 >> 6) + (w & 1);   // 64-centroid group index
  float ncv[4][4], sbv[4][4];
  #pragma unroll
  for (int mt = 0; mt < 4; ++mt)
    #pragma unroll
    for (int r = 0; r < 4; ++r) {
      const int k = bm0 + wm + mt * 16 + q * 4 + r;
      ncv[mt][r] = norm_cent[k];
      sbv[mt][r] = s_b[k];
    }

  #pragma unroll
  for (int nt = 0; nt < 4; ++nt) {
    const int t = bn0 + wn + nt * 16 + sub;
    const float sa2 = 2.0f * s_a[t];
    float d[4][4];
    float dmin = 3.4e38f;
    #pragma unroll
    for (int mt = 0; mt < 4; ++mt)
      #pragma unroll
      for (int r = 0; r < 4; ++r) {
        d[mt][r] = ncv[mt][r] - sa2 * sbv[mt][r] * (float)acc[mt][nt][r];
        dmin = fminf(dmin, d[mt][r]);
      }
    // fold across the 4 q-lanes holding this token
    dmin = fminf(dmin, __shfl_xor(dmin, 16, 64));
    dmin = fminf(dmin, __shfl_xor(dmin, 32, 64));
    const float thresh = dmin + DELTA;
    unsigned long long pm = 0;
    #pragma unroll
    for (int mt = 0; mt < 4; ++mt)
      #pragma unroll
      for (int r = 0; r < 4; ++r)
        if (d[mt][r] <= thresh) pm |= 1ull << (mt * 16 + q * 4 + r);
    pm |= (unsigned long long)__shfl_xor((long long)pm, 16, 64);
    pm |= (unsigned long long)__shfl_xor((long long)pm, 32, 64);
    if (q == 0) {
      LMin[(size_t)t * 128 + g] = dmin;
      Mask[(size_t)t * 128 + g] = pm;
    }
  }
}

// ------- D3: refine, wave per token (r6-proven), exact fp32 shifted distance -------
__global__ __launch_bounds__(256) void refine_kernel(
    const float* __restrict__ LMin, const unsigned long long* __restrict__ Mask,
    const float* __restrict__ rep, const float* __restrict__ cent,
    const float* __restrict__ norm_cent,
    float* __restrict__ out_tokens, float* __restrict__ out_q) {
  const int w = threadIdx.x >> 6, l = threadIdx.x & 63;
  const int t = blockIdx.x * 4 + w;
  if (t >= BT) return;

  const float lm0 = LMin[(size_t)t * 128 + l];
  const float lm1 = LMin[(size_t)t * 128 + 64 + l];
  float v = fminf(lm0, lm1);
  #pragma unroll
  for (int off = 32; off; off >>= 1) v = fminf(v, __shfl_xor(v, off, 64));
  const float thresh = v + DELTA;
  unsigned long long gm0 = __ballot(lm0 <= thresh);
  unsigned long long gm1 = __ballot(lm1 <= thresh);

  const int b_ = t >> 9, tt = t & 511;
  const float* rrow = rep + (size_t)(b_ * T_STRIDE + 1 + tt) * DD;
  unsigned long long bestE = ~0ull;   // lane 0 authoritative

  #pragma unroll
  for (int half = 0; half < 2; ++half) {
    unsigned long long gmask = half ? gm1 : gm0;
    while (gmask) {
      const int h = __ffsll((unsigned long long)gmask) - 1;
      gmask &= gmask - 1;
      unsigned long long mask = Mask[(size_t)t * 128 + half * 64 + h];
      while (mask) {
        const int bit = __ffsll((unsigned long long)mask) - 1;
        mask &= mask - 1;
        const int k = (half * 64 + h) * 64 + bit;
        const float* crow = cent + (size_t)k * DD;
        float part = 0.f;
        #pragma unroll
        for (int j = 0; j < 12; ++j)
          part += rrow[l + j * 64] * crow[l + j * 64];
        #pragma unroll
        for (int off = 32; off; off >>= 1) part += __shfl_down(part, off, 64);
        if (l == 0) {
          float d = norm_cent[k] - 2.0f * part;   // shifted exact (r9-validated)
          unsigned long long p =
              ((unsigned long long)sortable_bits(d) << 32) | (unsigned)k;
          if (p < bestE) bestE = p;
        }
      }
    }
  }
  int kb0 = (l == 0) ? (int)(bestE & 0xFFFFFFFFull) : 0;
  const int kbest = __shfl(kb0, 0, 64);
  if (l == 0) out_tokens[t] = (float)kbest;
  const float4* src = (const float4*)(cent + (size_t)kbest * DD);
  float4* dst = (float4*)(out_q + (size_t)t * DD);
  #pragma unroll
  for (int j = 0; j < 3; ++j) dst[l + j * 64] = src[l + j * 64];
}

// ================= tiny-ws fallback: fp32 vector GEMM + argmin =================
#define FBM 64
#define FBN 64
#define FBK 16
#define FNSPLIT 16
__global__ __launch_bounds__(256) void norms_only_kernel(
    const float* __restrict__ rep, const float* __restrict__ cent,
    float* __restrict__ norm_rep, float* __restrict__ norm_cent) {
  int wid  = (blockIdx.x * blockDim.x + threadIdx.x) >> 6;
  int lane = threadIdx.x & 63;
  const float* src;
  float* nd;
  if (wid < BT) {
    int b = wid >> 9, tt = wid & 511;
    src = rep + (size_t)(b * T_STRIDE + 1 + tt) * DD;
    nd = norm_rep + wid;
  } else {
    int k = wid - BT;
    if (k >= KC) return;
    src = cent + (size_t)k * DD;
    nd = norm_cent + k;
  }
  float s = 0.f;
  for (int j = lane; j < DD; j += 64) { float v = src[j]; s += v * v; }
  #pragma unroll
  for (int off = 32; off; off >>= 1) s += __shfl_down(s, off, 64);
  if (lane == 0) *nd = s;
}

__global__ __launch_bounds__(256) void fp32_argmin_gemm(
    const float* __restrict__ rep, const float* __restrict__ cent,
    const float* __restrict__ norm_rep, const float* __restrict__ norm_cent,
    unsigned long long* __restrict__ packed) {
  __shared__ float Asf[FBK][FBM];
  __shared__ float Bsf[FBK][FBN];
  const int tid = threadIdx.x;
  const int m0  = blockIdx.x * FBM;
  const int kbase = blockIdx.y * (KC / FNSPLIT);
  const int tx = tid & 15, ty = tid >> 4;
  const int ldr = tid >> 2, ldc = (tid & 3) * 4;
  const int t_ld = m0 + ldr;
  const float* arow =
      rep + (size_t)((t_ld >> 9) * T_STRIDE + 1 + (t_ld & 511)) * DD + ldc;
  unsigned long long best[4];
  #pragma unroll
  for (int i = 0; i < 4; ++i) best[i] = ~0ull;
  float nr[4];
  #pragma unroll
  for (int i = 0; i < 4; ++i) nr[i] = norm_rep[m0 + ty * 4 + i];
  for (int nt = 0; nt < (KC / FNSPLIT) / FBN; ++nt) {
    const int n0 = kbase + nt * FBN;
    const float* brow = cent + (size_t)(n0 + ldr) * DD + ldc;
    float acc[4][4];
    #pragma unroll
    for (int i = 0; i < 4; ++i)
      #pragma unroll
      for (int j = 0; j < 4; ++j) acc[i][j] = 0.f;
    for (int d0 = 0; d0 < DD; d0 += FBK) {
      float4 av = *(const float4*)(arow + d0);
      float4 bv = *(const float4*)(brow + d0);
      __syncthreads();
      Asf[ldc + 0][ldr] = av.x; Asf[ldc + 1][ldr] = av.y;
      Asf[ldc + 2][ldr] = av.z; Asf[ldc + 3][ldr] = av.w;
      Bsf[ldc + 0][ldr] = bv.x; Bsf[ldc + 1][ldr] = bv.y;
      Bsf[ldc + 2][ldr] = bv.z; Bsf[ldc + 3][ldr] = bv.w;
      __syncthreads();
      #pragma unroll
      for (int kk = 0; kk < FBK; ++kk) {
        float4 a4 = *(const float4*)&Asf[kk][ty * 4];
        float4 b4 = *(const float4*)&Bsf[kk][tx * 4];
        float a[4] = {a4.x, a4.y, a4.z, a4.w};
        float b[4] = {b4.x, b4.y, b4.z, b4.w};
        #pragma unroll
        for (int i = 0; i < 4; ++i)
          #pragma unroll
          for (int j = 0; j < 4; ++j) acc[i][j] += a[i] * b[j];
      }
    }
    #pragma unroll
    for (int i = 0; i < 4; ++i) {
      #pragma unroll
      for (int j = 0; j < 4; ++j) {
        int k = n0 + tx * 4 + j;
        float d = (nr[i] + norm_cent[k]) - 2.0f * acc[i][j];
        unsigned long long p =
            ((unsigned long long)sortable_bits(d) << 32) | (unsigned int)k;
        if (p < best[i]) best[i] = p;
      }
    }
  }
  #pragma unroll
  for (int off = 1; off < 16; off <<= 1) {
    #pragma unroll
    for (int i = 0; i < 4; ++i) {
      unsigned long long o =
          (unsigned long long)__shfl_xor((long long)best[i], off, 64);
      if (o < best[i]) best[i] = o;
    }
  }
  if (tx == 0) {
    #pragma unroll
    for (int i = 0; i < 4; ++i)
      atomicMin(&packed[m0 + ty * 4 + i], best[i]);
  }
}

__global__ __launch_bounds__(192) void gather_kernel(
    const unsigned long long* __restrict__ packed,
    const float* __restrict__ cent,
    float* __restrict__ out_tokens, float* __restrict__ out_q) {
  int t = blockIdx.x;
  unsigned int k = (unsigned int)(packed[t] & 0xFFFFFFFFull);
  if (threadIdx.x == 0) out_tokens[t] = (float)k;
  const float4* src = (const float4*)(cent + (size_t)k * DD);
  float4* dst = (float4*)(out_q + (size_t)t * DD);
  dst[threadIdx.x] = src[threadIdx.x];
}

extern "C" void kernel_launch(void* const* d_in, const int* in_sizes, int n_in,
                              void* d_out, int out_size, void* d_ws, size_t ws_size,
                              hipStream_t stream) {
  const float* rep  = (const float*)d_in[0];   // (8,513,768) fp32
  const float* cent = (const float*)d_in[1];   // (8192,768) fp32
  float* out = (float*)d_out;                  // [tokens(4096) | quantized(4096*768)]

  // layout: a8 | b8 | LMin | Mask | s_a | s_b | norm_cent
  const size_t SZ_A8 = (size_t)BT * DD;              //  3 MiB
  const size_t SZ_B8 = (size_t)KC * DD;              //  6 MiB
  const size_t SZ_LM = (size_t)BT * 128 * 4;         //  2 MiB
  const size_t SZ_MK = (size_t)BT * 128 * 8;         //  4 MiB
  const size_t OFF_SA = SZ_A8 + SZ_B8 + SZ_LM + SZ_MK;
  const size_t OFF_SB = OFF_SA + 16384;
  const size_t OFF_NC = OFF_SB + 32768;
  const size_t WS_A   = OFF_NC + 32768;

  if (ws_size >= WS_A) {
    int8_t* a8 = (int8_t*)d_ws;
    int8_t* b8 = (int8_t*)((char*)d_ws + SZ_A8);
    float* LMin = (float*)((char*)d_ws + SZ_A8 + SZ_B8);
    unsigned long long* Mask =
        (unsigned long long*)((char*)d_ws + SZ_A8 + SZ_B8 + SZ_LM);
    float* s_a = (float*)((char*)d_ws + OFF_SA);
    float* s_b = (float*)((char*)d_ws + OFF_SB);
    float* norm_cent = (float*)((char*)d_ws + OFF_NC);

    quant_kernel<<<3072, 256, 0, stream>>>(rep, cent, a8, b8, s_a, s_b,
                                           norm_cent);
    dim3 grid(KC / 128, BT / 128);
    mfma_i8_cand<<<grid, 256, 0, stream>>>(a8, b8, s_a, s_b, norm_cent,
                                           LMin, Mask);
    refine_kernel<<<BT / 4, 256, 0, stream>>>(LMin, Mask, rep, cent,
                                              norm_cent, out, out + BT);
  } else {
    unsigned long long* packed = (unsigned long long*)d_ws;
    float* norm_rep  = (float*)((char*)d_ws + 32768);
    float* norm_cent = (float*)((char*)d_ws + 49152);

    hipMemsetAsync(packed, 0xFF, BT * sizeof(unsigned long long), stream);
    norms_only_kernel<<<3072, 256, 0, stream>>>(rep, cent, norm_rep, norm_cent);
    dim3 grid(BT / FBM, FNSPLIT);
    fp32_argmin_gemm<<<grid, 256, 0, stream>>>(rep, cent, norm_rep, norm_cent,
                                               packed);
    gather_kernel<<<BT, 192, 0, stream>>>(packed, cent, out, out + BT);
  }
}